// Round 1
// baseline (3537.293 us; speedup 1.0000x reference)
//
#include <hip/hip_runtime.h>
#include <math.h>

#define NN 200000
#define EE 100000
#define RAWD 172
#define MEMD 100
#define NCOL 300   // 3*H
#define KI 480     // w_ih K (472) padded to 30*16
#define KH 112     // w_hh K (100) padded to 7*16
#define KTOT 592   // KI + KH
#define WTC 320    // padded col count (>= 311 needed by j=6 lanes), 16*320/256=20
#define BK 16
#define BM 32
#define TILES_I 30
#define TILES_ALL 37

// ---- kernel 1: per-node winner via packed atomicMax key = (t<<32)|(eid+1) ----
__global__ void k_winner(const int* __restrict__ src, const int* __restrict__ dst,
                         const int* __restrict__ t, unsigned long long* __restrict__ keys) {
    int e = blockIdx.x * blockDim.x + threadIdx.x;
    if (e >= 2 * EE) return;
    int re = (e < EE) ? e : e - EE;
    int node = (e < EE) ? src[re] : dst[re];
    unsigned long long key =
        ((unsigned long long)(unsigned)t[re] << 32) | (unsigned)(e + 1);
    atomicMax(&keys[node], key);
}

// ---- kernel 2: decode winner -> per-node info; also emit new_last_update ----
__global__ void k_nodeinfo(const unsigned long long* __restrict__ keys,
                           const int* __restrict__ src, const int* __restrict__ dst,
                           const int* __restrict__ lu,
                           int* __restrict__ other, int* __restrict__ ew,
                           float* __restrict__ dtv, float* __restrict__ out_lu) {
    int n = blockIdx.x * blockDim.x + threadIdx.x;
    if (n >= NN) return;
    unsigned long long k = keys[n];
    if (k != 0ull) {
        int w = (int)(k & 0xffffffffull) - 1;          // winner eid in [0,2E)
        int re = (w < EE) ? w : w - EE;                // edge row
        other[n] = (w < EE) ? dst[re] : src[re];       // the "other" endpoint
        ew[n] = re;
        int tt = (int)(k >> 32);
        dtv[n] = (float)tt - (float)lu[n];             // exact in f32
        out_lu[n] = (float)tt;
    } else {
        other[n] = 0;
        ew[n] = -1;                                    // has=false flag
        dtv[n] = 0.f;
        out_lu[n] = (float)lu[n];
    }
}

// ---- kernel 3: build padded transposed weight Wt[KTOT][WTC] ----
// rows 0..471 = w_ih^T, 472..479 = 0, 480..579 = w_hh^T, 580..591 = 0; cols>=300 = 0
__global__ void k_wt(const float* __restrict__ w_ih, const float* __restrict__ w_hh,
                     float* __restrict__ Wt) {
    int i = blockIdx.x * blockDim.x + threadIdx.x;
    if (i >= KTOT * WTC) return;
    int r = i / WTC, c = i % WTC;
    float v = 0.f;
    if (c < NCOL) {
        if (r < 472) v = w_ih[c * 472 + r];
        else if (r >= KI && r < KI + MEMD) v = w_hh[c * MEMD + (r - KI)];
    }
    Wt[i] = v;
}

// ---- kernel 4: fused gather + dual GEMM + GRU gates ----
// BM=32 nodes/block, 256 threads as (tm 0..15) x (tn 0..15).
// Thread owns nodes {tm, tm+16} and m-values {tn+16j}, cols {m, m+100, m+200}.
__global__ __launch_bounds__(256) void k_gemm(
    const float* __restrict__ memory, const float* __restrict__ raw_msg,
    const float* __restrict__ time_w, const float* __restrict__ time_b,
    const float* __restrict__ b_ih, const float* __restrict__ b_hh,
    const int* __restrict__ other, const int* __restrict__ ew,
    const float* __restrict__ dtv, const float* __restrict__ Wt,
    float* __restrict__ out_mem) {
    __shared__ float Xmem[BM][104];       // own-memory rows (persist; reused 3x)
    __shared__ float Ws[BK][WTC];         // W k-tile
    __shared__ float Xs[BM][BK];          // X k-tile
    __shared__ int s_other[BM];
    __shared__ int s_ew[BM];
    __shared__ float s_dt[BM];

    const int tid = threadIdx.x;
    const int nbase = blockIdx.x * BM;

    if (tid < BM) {
        s_other[tid] = other[nbase + tid];
        s_ew[tid] = ew[nbase + tid];
        s_dt[tid] = dtv[nbase + tid];
    }
    for (int f = tid; f < BM * MEMD; f += 256) {
        int n = f / MEMD, k = f - n * MEMD;
        Xmem[n][k] = memory[(size_t)(nbase + n) * MEMD + k];
    }
    __syncthreads();

    const int tm = tid >> 4, tn = tid & 15;
    float ai[2][7][3], ah[2][7][3];
#pragma unroll
    for (int i = 0; i < 2; ++i)
#pragma unroll
        for (int j = 0; j < 7; ++j)
#pragma unroll
            for (int p = 0; p < 3; ++p) { ai[i][j][p] = 0.f; ah[i][j][p] = 0.f; }

    auto do_tile = [&](int kt, float (&acc)[2][7][3]) {
        const int kbase = kt * BK;
        // stage W tile: straight contiguous 20KB copy
        const float* wsrc = Wt + (size_t)kbase * WTC;
        float* wdst = &Ws[0][0];
#pragma unroll
        for (int f = 0; f < (BK * WTC) / 256; ++f)
            wdst[tid + f * 256] = wsrc[tid + f * 256];
        // stage X tile: piecewise gather
#pragma unroll
        for (int f = 0; f < 2; ++f) {
            int idx = tid + f * 256;
            int n = idx >> 4, kk = idx & 15;
            int k = kbase + kk;
            int e = s_ew[n];
            float v = 0.f;
            if (k < 100) { if (e >= 0) v = Xmem[n][k]; }                     // memory[self]
            else if (k < 200) { if (e >= 0) v = memory[(size_t)s_other[n] * MEMD + (k - 100)]; }
            else if (k < 372) { if (e >= 0) v = raw_msg[(size_t)e * RAWD + (k - 200)]; }
            else if (k < 472) {
                if (e >= 0)
                    v = cosf(__fadd_rn(__fmul_rn(s_dt[n], time_w[k - 372]), time_b[k - 372]));
            }
            else if (k >= KI && k < KI + MEMD) v = Xmem[n][k - KI];          // gh input
            Xs[n][kk] = v;
        }
        __syncthreads();
#pragma unroll
        for (int kk = 0; kk < BK; ++kk) {
            float x0 = Xs[tm][kk];
            float x1 = Xs[tm + 16][kk];
#pragma unroll
            for (int j = 0; j < 7; ++j) {
                int m = tn + 16 * j;
#pragma unroll
                for (int p = 0; p < 3; ++p) {
                    float w = Ws[kk][m + p * 100];
                    acc[0][j][p] = fmaf(x0, w, acc[0][j][p]);
                    acc[1][j][p] = fmaf(x1, w, acc[1][j][p]);
                }
            }
        }
        __syncthreads();
    };

    for (int kt = 0; kt < TILES_I; ++kt) do_tile(kt, ai);        // gi part
    for (int kt = TILES_I; kt < TILES_ALL; ++kt) do_tile(kt, ah); // gh part

    // epilogue: GRU gates
#pragma unroll
    for (int i = 0; i < 2; ++i) {
        int n = tm + 16 * i;
        size_t gn = (size_t)(nbase + n);
#pragma unroll
        for (int j = 0; j < 7; ++j) {
            int m = tn + 16 * j;
            if (m < MEMD) {
                float gir = ai[i][j][0] + b_ih[m];
                float giz = ai[i][j][1] + b_ih[m + 100];
                float gin = ai[i][j][2] + b_ih[m + 200];
                float ghr = ah[i][j][0] + b_hh[m];
                float ghz = ah[i][j][1] + b_hh[m + 100];
                float ghn = ah[i][j][2] + b_hh[m + 200];
                float r = 1.f / (1.f + expf(-(gir + ghr)));
                float z = 1.f / (1.f + expf(-(giz + ghz)));
                float nv = tanhf(gin + r * ghn);
                out_mem[gn * MEMD + m] = (1.f - z) * nv + z * Xmem[n][m];
            }
        }
    }
}

extern "C" void kernel_launch(void* const* d_in, const int* in_sizes, int n_in,
                              void* d_out, int out_size, void* d_ws, size_t ws_size,
                              hipStream_t stream) {
    const float* memory = (const float*)d_in[0];
    const float* raw_msg = (const float*)d_in[1];
    const float* time_w = (const float*)d_in[2];
    const float* time_b = (const float*)d_in[3];
    const float* w_ih = (const float*)d_in[4];
    const float* w_hh = (const float*)d_in[5];
    const float* b_ih = (const float*)d_in[6];
    const float* b_hh = (const float*)d_in[7];
    const int* last_update = (const int*)d_in[8];
    const int* src = (const int*)d_in[9];
    const int* dst = (const int*)d_in[10];
    const int* t = (const int*)d_in[11];

    char* ws = (char*)d_ws;
    unsigned long long* keys = (unsigned long long*)ws;      // 1,600,000 B
    int* other = (int*)(ws + 1600000);                       //   800,000 B
    int* ew = (int*)(ws + 2400000);                          //   800,000 B
    float* dtv = (float*)(ws + 3200000);                     //   800,000 B
    float* Wt = (float*)(ws + 4000000);                      //   757,760 B

    float* out_mem = (float*)d_out;
    float* out_lu = (float*)d_out + (size_t)NN * MEMD;       // last_update as f32

    hipMemsetAsync(keys, 0, (size_t)NN * 8, stream);
    k_winner<<<(2 * EE + 255) / 256, 256, 0, stream>>>(src, dst, t, keys);
    k_nodeinfo<<<(NN + 255) / 256, 256, 0, stream>>>(keys, src, dst, last_update,
                                                     other, ew, dtv, out_lu);
    k_wt<<<(KTOT * WTC + 255) / 256, 256, 0, stream>>>(w_ih, w_hh, Wt);
    k_gemm<<<NN / BM, 256, 0, stream>>>(memory, raw_msg, time_w, time_b, b_ih, b_hh,
                                        other, ew, dtv, Wt, out_mem);
}

// Round 2
// 731.413 us; speedup vs baseline: 4.8362x; 4.8362x over previous
//
#include <hip/hip_runtime.h>
#include <hip/hip_bf16.h>
#include <math.h>

#define NN 200000
#define EE 100000
#define RAWD 172
#define MEMD 100
#define KTOT 608          // 480 (gi: 472 padded) + 128 (gh: 100 padded)
#define KI 480
#define NKT 19            // K steps of 32
#define NCT 21            // col tiles: 3 gates x 7 tiles (m padded 100->112)
#define RS 616            // X row stride in bf16 elems (pad for LDS banks)
#define BM 64             // nodes per block

typedef __attribute__((ext_vector_type(8))) short bf16x8;
typedef __attribute__((ext_vector_type(4))) float f32x4;

__device__ inline unsigned short f2bf(float v) {
    __hip_bfloat16 h = __float2bfloat16(v);
    unsigned short u; __builtin_memcpy(&u, &h, 2); return u;
}

// ---- kernel 1: per-node winner via packed atomicMax key = (t<<32)|(eid+1) ----
__global__ void k_winner(const int* __restrict__ src, const int* __restrict__ dst,
                         const int* __restrict__ t, unsigned long long* __restrict__ keys) {
    int e = blockIdx.x * blockDim.x + threadIdx.x;
    if (e >= 2 * EE) return;
    int re = (e < EE) ? e : e - EE;
    int node = (e < EE) ? src[re] : dst[re];
    unsigned long long key =
        ((unsigned long long)(unsigned)t[re] << 32) | (unsigned)(e + 1);
    atomicMax(&keys[node], key);
}

// ---- kernel 2: decode winner; emit new_last_update (as f32) ----
__global__ void k_nodeinfo(const unsigned long long* __restrict__ keys,
                           const int* __restrict__ src, const int* __restrict__ dst,
                           const int* __restrict__ lu,
                           int* __restrict__ other, int* __restrict__ ew,
                           float* __restrict__ dtv, float* __restrict__ out_lu) {
    int n = blockIdx.x * blockDim.x + threadIdx.x;
    if (n >= NN) return;
    unsigned long long k = keys[n];
    if (k != 0ull) {
        int w = (int)(k & 0xffffffffull) - 1;
        int re = (w < EE) ? w : w - EE;
        other[n] = (w < EE) ? dst[re] : src[re];
        ew[n] = re;
        int tt = (int)(k >> 32);
        dtv[n] = (float)tt - (float)lu[n];
        out_lu[n] = (float)tt;
    } else {
        other[n] = 0;
        ew[n] = -1;
        dtv[n] = 0.f;
        out_lu[n] = (float)lu[n];
    }
}

// ---- kernel 3: pack W into MFMA B-fragment order, bf16 ----
// frag fi = kt*NCT + ct; lane l holds k = kt*32 + (l>>4)*8 + j, outcol = ct*16 + (l&15).
// Column permutation: ct = p*7 + jm  ->  original col = p*100 + (jm*16 + (l&15)), p in {r,z,n}.
// K rows: 0..471 = w_ih^T ; 472..479 = 0 ; 480..579 = w_hh^T ; 580..607 = 0.
__global__ void k_pack(const float* __restrict__ w_ih, const float* __restrict__ w_hh,
                       unsigned short* __restrict__ Wb) {
    int id = blockIdx.x * blockDim.x + threadIdx.x;
    if (id >= NKT * NCT * 64) return;
    int lane = id & 63;
    int ct = (id >> 6) % NCT;
    int kt = id / (64 * NCT);
    int i = lane & 15, kl = lane >> 4;
    int m = (ct % 7) * 16 + i;
    int p = ct / 7;
    unsigned short o[8];
#pragma unroll
    for (int j = 0; j < 8; ++j) {
        int k = kt * 32 + kl * 8 + j;
        float v = 0.f;
        if (m < MEMD) {
            int c = p * MEMD + m;
            if (k < 472) v = w_ih[(size_t)c * 472 + k];
            else if (k >= KI && k < KI + MEMD) v = w_hh[(size_t)c * MEMD + (k - KI)];
        }
        o[j] = f2bf(v);
    }
    uint4 v4; __builtin_memcpy(&v4, o, 16);
    *reinterpret_cast<uint4*>(Wb + (size_t)id * 8) = v4;
}

// ---- kernel 4: fused gather + bf16 MFMA dual-GEMM + GRU gates ----
__global__ __launch_bounds__(256, 2) void k_fused(
    const float* __restrict__ memory, const float* __restrict__ raw_msg,
    const float* __restrict__ time_w, const float* __restrict__ time_b,
    const float* __restrict__ b_ih, const float* __restrict__ b_hh,
    const int* __restrict__ other, const int* __restrict__ ew,
    const float* __restrict__ dtv, const unsigned short* __restrict__ Wb,
    float* __restrict__ out_mem) {
    __shared__ unsigned short Xs[BM * RS];
    __shared__ int s_other[BM];
    __shared__ int s_ew[BM];
    __shared__ float s_dt[BM];

    const int tid = threadIdx.x;
    const int nbase = blockIdx.x * BM;

    if (tid < BM) {
        s_other[tid] = other[nbase + tid];
        s_ew[tid] = ew[nbase + tid];
        s_dt[tid] = dtv[nbase + tid];
    }
    __syncthreads();

    // build X tile [64][608] bf16 (row stride RS=616)
    for (int f = tid; f < BM * KTOT; f += 256) {
        int row = f / KTOT, k = f - row * KTOT;
        int e = s_ew[row];
        float v = 0.f;
        if (k < KI) {
            if (e >= 0) {
                if (k < 100)       v = memory[(size_t)(nbase + row) * MEMD + k];
                else if (k < 200)  v = memory[(size_t)s_other[row] * MEMD + (k - 100)];
                else if (k < 372)  v = raw_msg[(size_t)e * RAWD + (k - 200)];
                else if (k < 472)  v = cosf(__fadd_rn(__fmul_rn(s_dt[row], time_w[k - 372]),
                                                      time_b[k - 372]));
            }
        } else {
            int kk = k - KI;
            if (kk < MEMD) v = memory[(size_t)(nbase + row) * MEMD + kk];
        }
        Xs[row * RS + k] = f2bf(v);
    }
    __syncthreads();

    const int w = tid >> 6;
    const int l = tid & 63;
    const int lrow = l & 15, lk = l >> 4;

    f32x4 acc[NCT];
    f32x4 acch[7];
#pragma unroll
    for (int ct = 0; ct < NCT; ++ct) acc[ct] = (f32x4){0.f, 0.f, 0.f, 0.f};
#pragma unroll
    for (int ct = 0; ct < 7; ++ct) acch[ct] = (f32x4){0.f, 0.f, 0.f, 0.f};

    const unsigned short* xbase = &Xs[(16 * w + lrow) * RS + lk * 8];
    const bf16x8* Wbv = reinterpret_cast<const bf16x8*>(Wb);

    for (int kt = 0; kt < 15; ++kt) {
        bf16x8 a = *reinterpret_cast<const bf16x8*>(xbase + kt * 32);
#pragma unroll
        for (int ct = 0; ct < NCT; ++ct) {
            bf16x8 b = Wbv[(kt * NCT + ct) * 64 + l];
            acc[ct] = __builtin_amdgcn_mfma_f32_16x16x32_bf16(a, b, acc[ct], 0, 0, 0);
        }
    }
#pragma unroll
    for (int kt = 15; kt < NKT; ++kt) {
        bf16x8 a = *reinterpret_cast<const bf16x8*>(xbase + kt * 32);
#pragma unroll
        for (int ct = 0; ct < NCT; ++ct) {
            bf16x8 b = Wbv[(kt * NCT + ct) * 64 + l];
            acc[ct] = __builtin_amdgcn_mfma_f32_16x16x32_bf16(a, b, acc[ct], 0, 0, 0);
            if (ct >= 14)
                acch[ct - 14] = __builtin_amdgcn_mfma_f32_16x16x32_bf16(a, b, acch[ct - 14], 0, 0, 0);
        }
    }

    // epilogue: C layout col = lane&15, row = (lane>>4)*4 + reg
#pragma unroll
    for (int j = 0; j < 7; ++j) {
        int m = 16 * j + lrow;
        if (m < MEMD) {
            float bir = b_ih[m],       bhr = b_hh[m];
            float biz = b_ih[100 + m], bhz = b_hh[100 + m];
            float bin = b_ih[200 + m], bhn = b_hh[200 + m];
#pragma unroll
            for (int reg = 0; reg < 4; ++reg) {
                int row = 16 * w + lk * 4 + reg;
                size_t node = (size_t)(nbase + row);
                float rg = acc[j][reg] + bir + bhr;
                float zg = acc[7 + j][reg] + biz + bhz;
                float ghn = acch[j][reg] + bhn;
                float gin = (acc[14 + j][reg] - acch[j][reg]) + bin;
                float r = 1.f / (1.f + expf(-rg));
                float z = 1.f / (1.f + expf(-zg));
                float nv = tanhf(gin + r * ghn);
                float mo = memory[node * MEMD + m];
                out_mem[node * MEMD + m] = (1.f - z) * nv + z * mo;
            }
        }
    }
}

extern "C" void kernel_launch(void* const* d_in, const int* in_sizes, int n_in,
                              void* d_out, int out_size, void* d_ws, size_t ws_size,
                              hipStream_t stream) {
    const float* memory = (const float*)d_in[0];
    const float* raw_msg = (const float*)d_in[1];
    const float* time_w = (const float*)d_in[2];
    const float* time_b = (const float*)d_in[3];
    const float* w_ih = (const float*)d_in[4];
    const float* w_hh = (const float*)d_in[5];
    const float* b_ih = (const float*)d_in[6];
    const float* b_hh = (const float*)d_in[7];
    const int* last_update = (const int*)d_in[8];
    const int* src = (const int*)d_in[9];
    const int* dst = (const int*)d_in[10];
    const int* t = (const int*)d_in[11];

    char* ws = (char*)d_ws;
    unsigned long long* keys = (unsigned long long*)ws;       // 1,600,000 B
    int* other = (int*)(ws + 1600000);                        //   800,000 B
    int* ew = (int*)(ws + 2400000);                           //   800,000 B
    float* dtv = (float*)(ws + 3200000);                      //   800,000 B
    unsigned short* Wb = (unsigned short*)(ws + 4000000);     //   408,576 B

    float* out_mem = (float*)d_out;
    float* out_lu = (float*)d_out + (size_t)NN * MEMD;

    hipMemsetAsync(keys, 0, (size_t)NN * 8, stream);
    k_winner<<<(2 * EE + 255) / 256, 256, 0, stream>>>(src, dst, t, keys);
    k_nodeinfo<<<(NN + 255) / 256, 256, 0, stream>>>(keys, src, dst, last_update,
                                                     other, ew, dtv, out_lu);
    k_pack<<<(NKT * NCT * 64 + 255) / 256, 256, 0, stream>>>(w_ih, w_hh, Wb);
    k_fused<<<NN / BM, 256, 0, stream>>>(memory, raw_msg, time_w, time_b, b_ih, b_hh,
                                         other, ew, dtv, Wb, out_mem);
}

// Round 3
// 461.035 us; speedup vs baseline: 7.6725x; 1.5865x over previous
//
#include <hip/hip_runtime.h>
#include <hip/hip_bf16.h>
#include <math.h>

#define NN 200000
#define EE 100000
#define RAWD 172
#define MEMD 100
#define KTOT 608          // 480 (gi: 472 padded) + 128 (gh: 100 padded)
#define KI 480
#define NKT 19            // K steps of 32
#define NCT 21            // col tiles: 3 gates x 7 tiles (m padded 100->112)
#define RS 616            // X row stride in bf16 elems (pad for LDS banks)
#define BM 64             // nodes per block

typedef __attribute__((ext_vector_type(8))) short bf16x8;
typedef __attribute__((ext_vector_type(4))) float f32x4;

__device__ inline unsigned short f2bf(float v) {
    __hip_bfloat16 h = __float2bfloat16(v);
    unsigned short u; __builtin_memcpy(&u, &h, 2); return u;
}

__device__ inline ushort4 pack4(float4 v) {
    ushort4 r;
    r.x = f2bf(v.x); r.y = f2bf(v.y); r.z = f2bf(v.z); r.w = f2bf(v.w);
    return r;
}

// ---- kernel 1: per-node winner via packed atomicMax key = (t<<32)|(eid+1) ----
__global__ void k_winner(const int* __restrict__ src, const int* __restrict__ dst,
                         const int* __restrict__ t, unsigned long long* __restrict__ keys) {
    int e = blockIdx.x * blockDim.x + threadIdx.x;
    if (e >= 2 * EE) return;
    int re = (e < EE) ? e : e - EE;
    int node = (e < EE) ? src[re] : dst[re];
    unsigned long long key =
        ((unsigned long long)(unsigned)t[re] << 32) | (unsigned)(e + 1);
    atomicMax(&keys[node], key);
}

// ---- kernel 2: decode winner; emit new_last_update (as f32) ----
__global__ void k_nodeinfo(const unsigned long long* __restrict__ keys,
                           const int* __restrict__ src, const int* __restrict__ dst,
                           const int* __restrict__ lu,
                           int* __restrict__ other, int* __restrict__ ew,
                           float* __restrict__ dtv, float* __restrict__ out_lu) {
    int n = blockIdx.x * blockDim.x + threadIdx.x;
    if (n >= NN) return;
    unsigned long long k = keys[n];
    if (k != 0ull) {
        int w = (int)(k & 0xffffffffull) - 1;
        int re = (w < EE) ? w : w - EE;
        other[n] = (w < EE) ? dst[re] : src[re];
        ew[n] = re;
        int tt = (int)(k >> 32);
        dtv[n] = (float)tt - (float)lu[n];
        out_lu[n] = (float)tt;
    } else {
        other[n] = 0;
        ew[n] = -1;
        dtv[n] = 0.f;
        out_lu[n] = (float)lu[n];
    }
}

// ---- kernel 3: pack W into MFMA B-fragment order, bf16 ----
__global__ void k_pack(const float* __restrict__ w_ih, const float* __restrict__ w_hh,
                       unsigned short* __restrict__ Wb) {
    int id = blockIdx.x * blockDim.x + threadIdx.x;
    if (id >= NKT * NCT * 64) return;
    int lane = id & 63;
    int ct = (id >> 6) % NCT;
    int kt = id / (64 * NCT);
    int i = lane & 15, kl = lane >> 4;
    int m = (ct % 7) * 16 + i;
    int p = ct / 7;
    unsigned short o[8];
#pragma unroll
    for (int j = 0; j < 8; ++j) {
        int k = kt * 32 + kl * 8 + j;
        float v = 0.f;
        if (m < MEMD) {
            int c = p * MEMD + m;
            if (k < 472) v = w_ih[(size_t)c * 472 + k];
            else if (k >= KI && k < KI + MEMD) v = w_hh[(size_t)c * MEMD + (k - KI)];
        }
        o[j] = f2bf(v);
    }
    uint4 v4; __builtin_memcpy(&v4, o, 16);
    *reinterpret_cast<uint4*>(Wb + (size_t)id * 8) = v4;
}

// ---- kernel 4: fused gather + bf16 MFMA dual-GEMM + GRU gates ----
__global__ __launch_bounds__(256, 2) void k_fused(
    const float* __restrict__ memory, const float* __restrict__ raw_msg,
    const float* __restrict__ time_w, const float* __restrict__ time_b,
    const float* __restrict__ b_ih, const float* __restrict__ b_hh,
    const int* __restrict__ other, const int* __restrict__ ew,
    const float* __restrict__ dtv, const unsigned short* __restrict__ Wb,
    float* __restrict__ out_mem) {
    __shared__ unsigned short Xs[BM * RS];
    __shared__ int s_other[BM];
    __shared__ int s_ew[BM];
    __shared__ float s_dt[BM];

    const int tid = threadIdx.x;
    const int nbase = blockIdx.x * BM;

    if (tid < BM) {
        s_other[tid] = other[nbase + tid];
        s_ew[tid] = ew[nbase + tid];
        s_dt[tid] = dtv[nbase + tid];
    }
    __syncthreads();

    const ushort4 z4 = {0, 0, 0, 0};

    // seg B: other-node memory -> k in [100,200). Random gather: issue first.
    for (int i = tid; i < BM * 25; i += 256) {
        int row = i / 25, c = i - row * 25;
        int e = s_ew[row];
        float4 v = *reinterpret_cast<const float4*>(
            memory + (size_t)s_other[row] * MEMD + 4 * c);
        ushort4 h = (e >= 0) ? pack4(v) : z4;
        *reinterpret_cast<ushort4*>(&Xs[row * RS + 100 + 4 * c]) = h;
    }
    // seg C: raw_msg -> k in [200,372). Random gather.
    for (int i = tid; i < BM * 43; i += 256) {
        int row = i / 43, c = i - row * 43;
        int e = s_ew[row];
        int eb = e < 0 ? 0 : e;
        float4 v = *reinterpret_cast<const float4*>(
            raw_msg + (size_t)eb * RAWD + 4 * c);
        ushort4 h = (e >= 0) ? pack4(v) : z4;
        *reinterpret_cast<ushort4*>(&Xs[row * RS + 200 + 4 * c]) = h;
    }
    // seg A (+E): self memory -> k in [0,100) masked, and [480,580) always.
    for (int i = tid; i < BM * 25; i += 256) {
        int row = i / 25, c = i - row * 25;
        float4 v = *reinterpret_cast<const float4*>(
            memory + (size_t)(nbase + row) * MEMD + 4 * c);
        ushort4 h = pack4(v);
        *reinterpret_cast<ushort4*>(&Xs[row * RS + KI + 4 * c]) = h;
        ushort4 hm = (s_ew[row] >= 0) ? h : z4;
        *reinterpret_cast<ushort4*>(&Xs[row * RS + 4 * c]) = hm;
    }
    // seg D: time encoding cos(dt*w+b) -> k in [372,472).
    for (int i = tid; i < BM * 25; i += 256) {
        int row = i / 25, c = i - row * 25;
        int e = s_ew[row];
        float dt = s_dt[row];
        float4 wv = *reinterpret_cast<const float4*>(time_w + 4 * c);
        float4 bv = *reinterpret_cast<const float4*>(time_b + 4 * c);
        float4 v;
        v.x = cosf(__fadd_rn(__fmul_rn(dt, wv.x), bv.x));
        v.y = cosf(__fadd_rn(__fmul_rn(dt, wv.y), bv.y));
        v.z = cosf(__fadd_rn(__fmul_rn(dt, wv.z), bv.z));
        v.w = cosf(__fadd_rn(__fmul_rn(dt, wv.w), bv.w));
        ushort4 h = (e >= 0) ? pack4(v) : z4;
        *reinterpret_cast<ushort4*>(&Xs[row * RS + 372 + 4 * c]) = h;
    }
    // zero pads: k in [472,480) (2 chunks) and [580,608) (7 chunks)
    for (int i = tid; i < BM * 9; i += 256) {
        int row = i / 9, c = i - row * 9;
        int k = (c < 2) ? (472 + 4 * c) : (580 + 4 * (c - 2));
        *reinterpret_cast<ushort4*>(&Xs[row * RS + k]) = z4;
    }
    __syncthreads();

    const int w = tid >> 6;
    const int l = tid & 63;
    const int lrow = l & 15, lk = l >> 4;

    // prefetch epilogue memory values (latency hides under MFMA loop)
    float mo[7][4];
#pragma unroll
    for (int j = 0; j < 7; ++j) {
        int m = 16 * j + lrow;
        int mc = (m < MEMD) ? m : 0;
#pragma unroll
        for (int reg = 0; reg < 4; ++reg) {
            int row = 16 * w + lk * 4 + reg;
            mo[j][reg] = memory[(size_t)(nbase + row) * MEMD + mc];
        }
    }

    f32x4 acc[NCT];
    f32x4 acch[7];
#pragma unroll
    for (int ct = 0; ct < NCT; ++ct) acc[ct] = (f32x4){0.f, 0.f, 0.f, 0.f};
#pragma unroll
    for (int ct = 0; ct < 7; ++ct) acch[ct] = (f32x4){0.f, 0.f, 0.f, 0.f};

    const unsigned short* xbase = &Xs[(16 * w + lrow) * RS + lk * 8];
    const bf16x8* Wbv = reinterpret_cast<const bf16x8*>(Wb);

    for (int kt = 0; kt < 15; ++kt) {
        bf16x8 a = *reinterpret_cast<const bf16x8*>(xbase + kt * 32);
#pragma unroll
        for (int ct = 0; ct < NCT; ++ct) {
            bf16x8 b = Wbv[(kt * NCT + ct) * 64 + l];
            acc[ct] = __builtin_amdgcn_mfma_f32_16x16x32_bf16(a, b, acc[ct], 0, 0, 0);
        }
    }
#pragma unroll
    for (int kt = 15; kt < NKT; ++kt) {
        bf16x8 a = *reinterpret_cast<const bf16x8*>(xbase + kt * 32);
#pragma unroll
        for (int ct = 0; ct < NCT; ++ct) {
            bf16x8 b = Wbv[(kt * NCT + ct) * 64 + l];
            acc[ct] = __builtin_amdgcn_mfma_f32_16x16x32_bf16(a, b, acc[ct], 0, 0, 0);
            if (ct >= 14)
                acch[ct - 14] = __builtin_amdgcn_mfma_f32_16x16x32_bf16(a, b, acch[ct - 14], 0, 0, 0);
        }
    }

    // epilogue: C layout col = lane&15, row = (lane>>4)*4 + reg
#pragma unroll
    for (int j = 0; j < 7; ++j) {
        int m = 16 * j + lrow;
        if (m < MEMD) {
            float bir = b_ih[m],       bhr = b_hh[m];
            float biz = b_ih[100 + m], bhz = b_hh[100 + m];
            float bin = b_ih[200 + m], bhn = b_hh[200 + m];
#pragma unroll
            for (int reg = 0; reg < 4; ++reg) {
                int row = 16 * w + lk * 4 + reg;
                size_t node = (size_t)(nbase + row);
                float rg = acc[j][reg] + bir + bhr;
                float zg = acc[7 + j][reg] + biz + bhz;
                float ghn = acch[j][reg] + bhn;
                float gin = (acc[14 + j][reg] - acch[j][reg]) + bin;
                float r = 1.f / (1.f + expf(-rg));
                float z = 1.f / (1.f + expf(-zg));
                float nv = tanhf(gin + r * ghn);
                out_mem[node * MEMD + m] = (1.f - z) * nv + z * mo[j][reg];
            }
        }
    }
}

extern "C" void kernel_launch(void* const* d_in, const int* in_sizes, int n_in,
                              void* d_out, int out_size, void* d_ws, size_t ws_size,
                              hipStream_t stream) {
    const float* memory = (const float*)d_in[0];
    const float* raw_msg = (const float*)d_in[1];
    const float* time_w = (const float*)d_in[2];
    const float* time_b = (const float*)d_in[3];
    const float* w_ih = (const float*)d_in[4];
    const float* w_hh = (const float*)d_in[5];
    const float* b_ih = (const float*)d_in[6];
    const float* b_hh = (const float*)d_in[7];
    const int* last_update = (const int*)d_in[8];
    const int* src = (const int*)d_in[9];
    const int* dst = (const int*)d_in[10];
    const int* t = (const int*)d_in[11];

    char* ws = (char*)d_ws;
    unsigned long long* keys = (unsigned long long*)ws;       // 1,600,000 B
    int* other = (int*)(ws + 1600000);                        //   800,000 B
    int* ew = (int*)(ws + 2400000);                           //   800,000 B
    float* dtv = (float*)(ws + 3200000);                      //   800,000 B
    unsigned short* Wb = (unsigned short*)(ws + 4000000);     //   408,576 B

    float* out_mem = (float*)d_out;
    float* out_lu = (float*)d_out + (size_t)NN * MEMD;

    hipMemsetAsync(keys, 0, (size_t)NN * 8, stream);
    k_winner<<<(2 * EE + 255) / 256, 256, 0, stream>>>(src, dst, t, keys);
    k_nodeinfo<<<(NN + 255) / 256, 256, 0, stream>>>(keys, src, dst, last_update,
                                                     other, ew, dtv, out_lu);
    k_pack<<<(NKT * NCT * 64 + 255) / 256, 256, 0, stream>>>(w_ih, w_hh, Wb);
    k_fused<<<NN / BM, 256, 0, stream>>>(memory, raw_msg, time_w, time_b, b_ih, b_hh,
                                         other, ew, dtv, Wb, out_mem);
}

// Round 4
// 408.575 us; speedup vs baseline: 8.6576x; 1.1284x over previous
//
#include <hip/hip_runtime.h>
#include <hip/hip_bf16.h>
#include <math.h>

#define NN 200000
#define EE 100000
#define RAWD 172
#define MEMD 100
#define KTOT 608          // 480 (gi: 472 padded) + 128 (gh: 100 padded)
#define KI 480
#define NKT 19            // K steps of 32
#define NCT 21            // col tiles: 3 gates x 7 tiles (m padded 100->112)
#define RS 616            // X row stride in bf16 elems (pad for LDS banks)
#define BM 64             // nodes per block

typedef __attribute__((ext_vector_type(8))) short bf16x8;
typedef __attribute__((ext_vector_type(4))) float f32x4;

__device__ inline unsigned short f2bf(float v) {
    __hip_bfloat16 h = __float2bfloat16(v);
    unsigned short u; __builtin_memcpy(&u, &h, 2); return u;
}

__device__ inline ushort4 pack4(float4 v) {
    ushort4 r;
    r.x = f2bf(v.x); r.y = f2bf(v.y); r.z = f2bf(v.z); r.w = f2bf(v.w);
    return r;
}

__device__ inline float fsigmoid(float x) { return 1.f / (1.f + __expf(-x)); }
__device__ inline float ftanh(float x) { return 1.f - 2.f / (__expf(2.f * x) + 1.f); }

// ---- kernel 1: per-node winner via packed atomicMax key = (t<<32)|(eid+1) ----
__global__ void k_winner(const int* __restrict__ src, const int* __restrict__ dst,
                         const int* __restrict__ t, unsigned long long* __restrict__ keys) {
    int e = blockIdx.x * blockDim.x + threadIdx.x;
    if (e >= 2 * EE) return;
    int re = (e < EE) ? e : e - EE;
    int node = (e < EE) ? src[re] : dst[re];
    unsigned long long key =
        ((unsigned long long)(unsigned)t[re] << 32) | (unsigned)(e + 1);
    atomicMax(&keys[node], key);
}

// ---- kernel 2: decode winner; emit new_last_update (as f32) ----
__global__ void k_nodeinfo(const unsigned long long* __restrict__ keys,
                           const int* __restrict__ src, const int* __restrict__ dst,
                           const int* __restrict__ lu,
                           int* __restrict__ other, int* __restrict__ ew,
                           float* __restrict__ dtv, float* __restrict__ out_lu) {
    int n = blockIdx.x * blockDim.x + threadIdx.x;
    if (n >= NN) return;
    unsigned long long k = keys[n];
    if (k != 0ull) {
        int w = (int)(k & 0xffffffffull) - 1;
        int re = (w < EE) ? w : w - EE;
        other[n] = (w < EE) ? dst[re] : src[re];
        ew[n] = re;
        int tt = (int)(k >> 32);
        dtv[n] = (float)tt - (float)lu[n];
        out_lu[n] = (float)tt;
    } else {
        other[n] = 0;
        ew[n] = -1;
        dtv[n] = 0.f;
        out_lu[n] = (float)lu[n];
    }
}

// ---- kernel 3: pack W into MFMA B-fragment order, bf16 ----
__global__ void k_pack(const float* __restrict__ w_ih, const float* __restrict__ w_hh,
                       unsigned short* __restrict__ Wb) {
    int id = blockIdx.x * blockDim.x + threadIdx.x;
    if (id >= NKT * NCT * 64) return;
    int lane = id & 63;
    int ct = (id >> 6) % NCT;
    int kt = id / (64 * NCT);
    int i = lane & 15, kl = lane >> 4;
    int m = (ct % 7) * 16 + i;
    int p = ct / 7;
    unsigned short o[8];
#pragma unroll
    for (int j = 0; j < 8; ++j) {
        int k = kt * 32 + kl * 8 + j;
        float v = 0.f;
        if (m < MEMD) {
            int c = p * MEMD + m;
            if (k < 472) v = w_ih[(size_t)c * 472 + k];
            else if (k >= KI && k < KI + MEMD) v = w_hh[(size_t)c * MEMD + (k - KI)];
        }
        o[j] = f2bf(v);
    }
    uint4 v4; __builtin_memcpy(&v4, o, 16);
    *reinterpret_cast<uint4*>(Wb + (size_t)id * 8) = v4;
}

// ---- kernel 4: fused gather + bf16 MFMA dual-GEMM + GRU gates ----
__global__ __launch_bounds__(256, 2) void k_fused(
    const float* __restrict__ memory, const float* __restrict__ raw_msg,
    const float* __restrict__ time_w, const float* __restrict__ time_b,
    const float* __restrict__ b_ih, const float* __restrict__ b_hh,
    const int* __restrict__ other, const int* __restrict__ ew,
    const float* __restrict__ dtv, const unsigned short* __restrict__ Wb,
    float* __restrict__ out_mem) {
    __shared__ unsigned short Xs[BM * RS];
    __shared__ int s_other[BM];
    __shared__ int s_ew[BM];
    __shared__ float s_dt[BM];

    const int tid = threadIdx.x;
    const int nbase = blockIdx.x * BM;

    if (tid < BM) {
        s_other[tid] = other[nbase + tid];
        s_ew[tid] = ew[nbase + tid];
        s_dt[tid] = dtv[nbase + tid];
    }
    __syncthreads();

    const ushort4 z4 = {0, 0, 0, 0};

    // seg B: other-node memory -> k in [100,200). Random gather: issue first.
    for (int i = tid; i < BM * 25; i += 256) {
        int row = i / 25, c = i - row * 25;
        int e = s_ew[row];
        float4 v = *reinterpret_cast<const float4*>(
            memory + (size_t)s_other[row] * MEMD + 4 * c);
        ushort4 h = (e >= 0) ? pack4(v) : z4;
        *reinterpret_cast<ushort4*>(&Xs[row * RS + 100 + 4 * c]) = h;
    }
    // seg C: raw_msg -> k in [200,372). Random gather.
    for (int i = tid; i < BM * 43; i += 256) {
        int row = i / 43, c = i - row * 43;
        int e = s_ew[row];
        int eb = e < 0 ? 0 : e;
        float4 v = *reinterpret_cast<const float4*>(
            raw_msg + (size_t)eb * RAWD + 4 * c);
        ushort4 h = (e >= 0) ? pack4(v) : z4;
        *reinterpret_cast<ushort4*>(&Xs[row * RS + 200 + 4 * c]) = h;
    }
    // seg A (+E): self memory -> k in [0,100) masked, and [480,580) always.
    for (int i = tid; i < BM * 25; i += 256) {
        int row = i / 25, c = i - row * 25;
        float4 v = *reinterpret_cast<const float4*>(
            memory + (size_t)(nbase + row) * MEMD + 4 * c);
        ushort4 h = pack4(v);
        *reinterpret_cast<ushort4*>(&Xs[row * RS + KI + 4 * c]) = h;
        ushort4 hm = (s_ew[row] >= 0) ? h : z4;
        *reinterpret_cast<ushort4*>(&Xs[row * RS + 4 * c]) = hm;
    }
    // seg D: time encoding cos(dt*w+b) -> k in [372,472).
    for (int i = tid; i < BM * 25; i += 256) {
        int row = i / 25, c = i - row * 25;
        int e = s_ew[row];
        float dt = s_dt[row];
        float4 wv = *reinterpret_cast<const float4*>(time_w + 4 * c);
        float4 bv = *reinterpret_cast<const float4*>(time_b + 4 * c);
        float4 v;
        v.x = cosf(__fadd_rn(__fmul_rn(dt, wv.x), bv.x));
        v.y = cosf(__fadd_rn(__fmul_rn(dt, wv.y), bv.y));
        v.z = cosf(__fadd_rn(__fmul_rn(dt, wv.z), bv.z));
        v.w = cosf(__fadd_rn(__fmul_rn(dt, wv.w), bv.w));
        ushort4 h = (e >= 0) ? pack4(v) : z4;
        *reinterpret_cast<ushort4*>(&Xs[row * RS + 372 + 4 * c]) = h;
    }
    // zero pads: k in [472,480) (2 chunks) and [580,608) (7 chunks)
    for (int i = tid; i < BM * 9; i += 256) {
        int row = i / 9, c = i - row * 9;
        int k = (c < 2) ? (472 + 4 * c) : (580 + 4 * (c - 2));
        *reinterpret_cast<ushort4*>(&Xs[row * RS + k]) = z4;
    }
    __syncthreads();

    const int w = tid >> 6;
    const int l = tid & 63;
    const int lrow = l & 15, lk = l >> 4;

    // prefetch epilogue memory values (latency hides under MFMA loop)
    float mo[7][4];
#pragma unroll
    for (int j = 0; j < 7; ++j) {
        int m = 16 * j + lrow;
        int mc = (m < MEMD) ? m : 0;
#pragma unroll
        for (int reg = 0; reg < 4; ++reg) {
            int row = 16 * w + lk * 4 + reg;
            mo[j][reg] = memory[(size_t)(nbase + row) * MEMD + mc];
        }
    }

    f32x4 acc[NCT];
    f32x4 acch[7];
#pragma unroll
    for (int ct = 0; ct < NCT; ++ct) acc[ct] = (f32x4){0.f, 0.f, 0.f, 0.f};
#pragma unroll
    for (int ct = 0; ct < 7; ++ct) acch[ct] = (f32x4){0.f, 0.f, 0.f, 0.f};

    const unsigned short* xbase = &Xs[(16 * w + lrow) * RS + lk * 8];
    const bf16x8* Wbv = reinterpret_cast<const bf16x8*>(Wb);

    // K-loop rotation: each block starts at a different k-tile so concurrent
    // blocks read DIFFERENT slices of Wb (spreads L2 bank pressure; the sum
    // over kt is order-independent).
    const int r15 = blockIdx.x % 15;
    for (int i = 0; i < 15; ++i) {
        int kt = r15 + i; if (kt >= 15) kt -= 15;
        bf16x8 a = *reinterpret_cast<const bf16x8*>(xbase + kt * 32);
#pragma unroll
        for (int ct = 0; ct < NCT; ++ct) {
            bf16x8 b = Wbv[(kt * NCT + ct) * 64 + l];
            acc[ct] = __builtin_amdgcn_mfma_f32_16x16x32_bf16(a, b, acc[ct], 0, 0, 0);
        }
    }
    const int r4 = blockIdx.x & 3;
    for (int i = 0; i < 4; ++i) {
        int kt = 15 + ((r4 + i) & 3);
        bf16x8 a = *reinterpret_cast<const bf16x8*>(xbase + kt * 32);
#pragma unroll
        for (int ct = 0; ct < NCT; ++ct) {
            bf16x8 b = Wbv[(kt * NCT + ct) * 64 + l];
            acc[ct] = __builtin_amdgcn_mfma_f32_16x16x32_bf16(a, b, acc[ct], 0, 0, 0);
            if (ct >= 14)
                acch[ct - 14] = __builtin_amdgcn_mfma_f32_16x16x32_bf16(a, b, acch[ct - 14], 0, 0, 0);
        }
    }

    // epilogue: C layout col = lane&15, row = (lane>>4)*4 + reg
#pragma unroll
    for (int j = 0; j < 7; ++j) {
        int m = 16 * j + lrow;
        if (m < MEMD) {
            float bir = b_ih[m],       bhr = b_hh[m];
            float biz = b_ih[100 + m], bhz = b_hh[100 + m];
            float bin = b_ih[200 + m], bhn = b_hh[200 + m];
#pragma unroll
            for (int reg = 0; reg < 4; ++reg) {
                int row = 16 * w + lk * 4 + reg;
                size_t node = (size_t)(nbase + row);
                float rg = acc[j][reg] + bir + bhr;
                float zg = acc[7 + j][reg] + biz + bhz;
                float ghn = acch[j][reg] + bhn;
                float gin = (acc[14 + j][reg] - acch[j][reg]) + bin;
                float r = fsigmoid(rg);
                float z = fsigmoid(zg);
                float nv = ftanh(gin + r * ghn);
                out_mem[node * MEMD + m] = (1.f - z) * nv + z * mo[j][reg];
            }
        }
    }
}

extern "C" void kernel_launch(void* const* d_in, const int* in_sizes, int n_in,
                              void* d_out, int out_size, void* d_ws, size_t ws_size,
                              hipStream_t stream) {
    const float* memory = (const float*)d_in[0];
    const float* raw_msg = (const float*)d_in[1];
    const float* time_w = (const float*)d_in[2];
    const float* time_b = (const float*)d_in[3];
    const float* w_ih = (const float*)d_in[4];
    const float* w_hh = (const float*)d_in[5];
    const float* b_ih = (const float*)d_in[6];
    const float* b_hh = (const float*)d_in[7];
    const int* last_update = (const int*)d_in[8];
    const int* src = (const int*)d_in[9];
    const int* dst = (const int*)d_in[10];
    const int* t = (const int*)d_in[11];

    char* ws = (char*)d_ws;
    unsigned long long* keys = (unsigned long long*)ws;       // 1,600,000 B
    int* other = (int*)(ws + 1600000);                        //   800,000 B
    int* ew = (int*)(ws + 2400000);                           //   800,000 B
    float* dtv = (float*)(ws + 3200000);                      //   800,000 B
    unsigned short* Wb = (unsigned short*)(ws + 4000000);     //   408,576 B

    float* out_mem = (float*)d_out;
    float* out_lu = (float*)d_out + (size_t)NN * MEMD;

    hipMemsetAsync(keys, 0, (size_t)NN * 8, stream);
    k_winner<<<(2 * EE + 255) / 256, 256, 0, stream>>>(src, dst, t, keys);
    k_nodeinfo<<<(NN + 255) / 256, 256, 0, stream>>>(keys, src, dst, last_update,
                                                     other, ew, dtv, out_lu);
    k_pack<<<(NKT * NCT * 64 + 255) / 256, 256, 0, stream>>>(w_ih, w_hh, Wb);
    k_fused<<<NN / BM, 256, 0, stream>>>(memory, raw_msg, time_w, time_b, b_ih, b_hh,
                                         other, ew, dtv, Wb, out_mem);
}

// Round 5
// 281.898 us; speedup vs baseline: 12.5481x; 1.4494x over previous
//
#include <hip/hip_runtime.h>
#include <hip/hip_bf16.h>
#include <math.h>

#define NN 200000
#define EE 100000
#define RAWD 172
#define MEMD 100
#define KTOT 608          // 480 (gi: 472 padded) + 128 (gh: 100 padded)
#define KI 480
#define NKT 19            // K steps of 32
#define NCT 21            // col tiles: 3 gates x 7 tiles (m padded 100->112)
#define RS 616            // X row stride in bf16 elems
#define BM 64             // nodes per block
#define PLN 113           // plane stride (112 + 1 pad)

typedef __attribute__((ext_vector_type(8))) short bf16x8;
typedef __attribute__((ext_vector_type(4))) float f32x4;

__device__ inline unsigned short f2bf(float v) {
    __hip_bfloat16 h = __float2bfloat16(v);
    unsigned short u; __builtin_memcpy(&u, &h, 2); return u;
}

__device__ inline ushort4 pack4(float4 v) {
    ushort4 r;
    r.x = f2bf(v.x); r.y = f2bf(v.y); r.z = f2bf(v.z); r.w = f2bf(v.w);
    return r;
}

__device__ inline float fsigmoid(float x) { return 1.f / (1.f + __expf(-x)); }
__device__ inline float ftanh(float x) { return 1.f - 2.f / (__expf(2.f * x) + 1.f); }

// ---- kernel 1: per-node winner via packed atomicMax key = (t<<32)|(eid+1) ----
__global__ void k_winner(const int* __restrict__ src, const int* __restrict__ dst,
                         const int* __restrict__ t, unsigned long long* __restrict__ keys) {
    int e = blockIdx.x * blockDim.x + threadIdx.x;
    if (e >= 2 * EE) return;
    int re = (e < EE) ? e : e - EE;
    int node = (e < EE) ? src[re] : dst[re];
    unsigned long long key =
        ((unsigned long long)(unsigned)t[re] << 32) | (unsigned)(e + 1);
    atomicMax(&keys[node], key);
}

// ---- kernel 2: decode winner; emit new_last_update (as f32) ----
__global__ void k_nodeinfo(const unsigned long long* __restrict__ keys,
                           const int* __restrict__ src, const int* __restrict__ dst,
                           const int* __restrict__ lu,
                           int* __restrict__ other, int* __restrict__ ew,
                           float* __restrict__ dtv, float* __restrict__ out_lu) {
    int n = blockIdx.x * blockDim.x + threadIdx.x;
    if (n >= NN) return;
    unsigned long long k = keys[n];
    if (k != 0ull) {
        int w = (int)(k & 0xffffffffull) - 1;
        int re = (w < EE) ? w : w - EE;
        other[n] = (w < EE) ? dst[re] : src[re];
        ew[n] = re;
        int tt = (int)(k >> 32);
        dtv[n] = (float)tt - (float)lu[n];
        out_lu[n] = (float)tt;
    } else {
        other[n] = 0;
        ew[n] = -1;
        dtv[n] = 0.f;
        out_lu[n] = (float)lu[n];
    }
}

// ---- kernel 3: pack W into MFMA B-fragment order, bf16 ----
__global__ void k_pack(const float* __restrict__ w_ih, const float* __restrict__ w_hh,
                       unsigned short* __restrict__ Wb) {
    int id = blockIdx.x * blockDim.x + threadIdx.x;
    if (id >= NKT * NCT * 64) return;
    int lane = id & 63;
    int ct = (id >> 6) % NCT;
    int kt = id / (64 * NCT);
    int i = lane & 15, kl = lane >> 4;
    int m = (ct % 7) * 16 + i;
    int p = ct / 7;
    unsigned short o[8];
#pragma unroll
    for (int j = 0; j < 8; ++j) {
        int k = kt * 32 + kl * 8 + j;
        float v = 0.f;
        if (m < MEMD) {
            int c = p * MEMD + m;
            if (k < 472) v = w_ih[(size_t)c * 472 + k];
            else if (k >= KI && k < KI + MEMD) v = w_hh[(size_t)c * MEMD + (k - KI)];
        }
        o[j] = f2bf(v);
    }
    uint4 v4; __builtin_memcpy(&v4, o, 16);
    *reinterpret_cast<uint4*>(Wb + (size_t)id * 8) = v4;
}

// ---- kernel 4: fused gather + bf16 MFMA dual-GEMM + GRU gates ----
// Wave w owns col-tiles ct = w, w+4, ... (6/5/5/5) for ALL 64 rows:
// each B fragment is loaded once per block (4x less L2 traffic than row-split).
__global__ __launch_bounds__(256, 2) void k_fused(
    const float* __restrict__ memory, const float* __restrict__ raw_msg,
    const float* __restrict__ time_w, const float* __restrict__ time_b,
    const float* __restrict__ b_ih, const float* __restrict__ b_hh,
    const int* __restrict__ other, const int* __restrict__ ew,
    const float* __restrict__ dtv, const unsigned short* __restrict__ Wb,
    float* __restrict__ out_mem) {
    // union: Xs (64*616*2 = 78848 B) while building/MFMA; 4 f32 planes
    // (4*32*113*4 = 57856 B) for the epilogue exchange.
    __shared__ alignas(16) char smem[BM * RS * 2];
    unsigned short* Xs = reinterpret_cast<unsigned short*>(smem);
    float* planes = reinterpret_cast<float*>(smem);
    __shared__ int s_other[BM];
    __shared__ int s_ew[BM];
    __shared__ float s_dt[BM];

    const int tid = threadIdx.x;
    const int nbase = blockIdx.x * BM;

    if (tid < BM) {
        s_other[tid] = other[nbase + tid];
        s_ew[tid] = ew[nbase + tid];
        s_dt[tid] = dtv[nbase + tid];
    }
    __syncthreads();

    const ushort4 z4 = {0, 0, 0, 0};

    // seg B: other-node memory -> k in [100,200). Random gather: issue first.
    for (int i = tid; i < BM * 25; i += 256) {
        int row = i / 25, c = i - row * 25;
        int e = s_ew[row];
        float4 v = *reinterpret_cast<const float4*>(
            memory + (size_t)s_other[row] * MEMD + 4 * c);
        ushort4 h = (e >= 0) ? pack4(v) : z4;
        *reinterpret_cast<ushort4*>(&Xs[row * RS + 100 + 4 * c]) = h;
    }
    // seg C: raw_msg -> k in [200,372). Random gather.
    for (int i = tid; i < BM * 43; i += 256) {
        int row = i / 43, c = i - row * 43;
        int e = s_ew[row];
        int eb = e < 0 ? 0 : e;
        float4 v = *reinterpret_cast<const float4*>(
            raw_msg + (size_t)eb * RAWD + 4 * c);
        ushort4 h = (e >= 0) ? pack4(v) : z4;
        *reinterpret_cast<ushort4*>(&Xs[row * RS + 200 + 4 * c]) = h;
    }
    // seg A (+E): self memory -> k in [0,100) masked, and [480,580) always.
    for (int i = tid; i < BM * 25; i += 256) {
        int row = i / 25, c = i - row * 25;
        float4 v = *reinterpret_cast<const float4*>(
            memory + (size_t)(nbase + row) * MEMD + 4 * c);
        ushort4 h = pack4(v);
        *reinterpret_cast<ushort4*>(&Xs[row * RS + KI + 4 * c]) = h;
        ushort4 hm = (s_ew[row] >= 0) ? h : z4;
        *reinterpret_cast<ushort4*>(&Xs[row * RS + 4 * c]) = hm;
    }
    // seg D: time encoding cos(dt*w+b) -> k in [372,472).
    for (int i = tid; i < BM * 25; i += 256) {
        int row = i / 25, c = i - row * 25;
        int e = s_ew[row];
        float dt = s_dt[row];
        float4 wv = *reinterpret_cast<const float4*>(time_w + 4 * c);
        float4 bv = *reinterpret_cast<const float4*>(time_b + 4 * c);
        float4 v;
        v.x = cosf(__fadd_rn(__fmul_rn(dt, wv.x), bv.x));
        v.y = cosf(__fadd_rn(__fmul_rn(dt, wv.y), bv.y));
        v.z = cosf(__fadd_rn(__fmul_rn(dt, wv.z), bv.z));
        v.w = cosf(__fadd_rn(__fmul_rn(dt, wv.w), bv.w));
        ushort4 h = (e >= 0) ? pack4(v) : z4;
        *reinterpret_cast<ushort4*>(&Xs[row * RS + 372 + 4 * c]) = h;
    }
    // zero pads: k in [472,480) and [580,608)
    for (int i = tid; i < BM * 9; i += 256) {
        int row = i / 9, c = i - row * 9;
        int k = (c < 2) ? (472 + 4 * c) : (580 + 4 * (c - 2));
        *reinterpret_cast<ushort4*>(&Xs[row * RS + k]) = z4;
    }
    __syncthreads();

    const int w = tid >> 6;
    const int l = tid & 63;
    const int lrow = l & 15, lk = l >> 4;

    f32x4 acc[6][4];           // [owned ct][rowgroup]
    f32x4 acch[3][4];          // gh-only accumulators for owned ct>=14 (i-3)
#pragma unroll
    for (int i = 0; i < 6; ++i)
#pragma unroll
        for (int rg = 0; rg < 4; ++rg) acc[i][rg] = (f32x4){0.f, 0.f, 0.f, 0.f};
#pragma unroll
    for (int i = 0; i < 3; ++i)
#pragma unroll
        for (int rg = 0; rg < 4; ++rg) acch[i][rg] = (f32x4){0.f, 0.f, 0.f, 0.f};

    const bf16x8* Wbv = reinterpret_cast<const bf16x8*>(Wb);
    const int r15 = blockIdx.x % 15;
    const int r4 = blockIdx.x & 3;

    // schedule: idx 0..14 -> rotated main k-tiles; 15..18 -> rotated tail
    auto ktof = [&](int idx) {
        if (idx < 15) { int k = r15 + idx; return k >= 15 ? k - 15 : k; }
        int k = r4 + (idx - 15); return 15 + (k >= 4 ? k - 4 : k);
    };

    bf16x8 b[6];
    {
        int kt0 = ktof(0);
#pragma unroll
        for (int i = 0; i < 6; ++i) {
            int ct = w + 4 * i;
            if (ct < NCT) b[i] = Wbv[(kt0 * NCT + ct) * 64 + l];
        }
    }

    for (int idx = 0; idx < NKT; ++idx) {
        int kt = ktof(idx);
        // 1-deep B prefetch for next k-tile
        bf16x8 bn[6];
#pragma unroll
        for (int i = 0; i < 6; ++i) bn[i] = b[i];
        if (idx + 1 < NKT) {
            int ktn = ktof(idx + 1);
#pragma unroll
            for (int i = 0; i < 6; ++i) {
                int ct = w + 4 * i;
                if (ct < NCT) bn[i] = Wbv[(ktn * NCT + ct) * 64 + l];
            }
        }
        // A fragments: all 4 rowgroups for this k-tile
        bf16x8 a[4];
#pragma unroll
        for (int rg = 0; rg < 4; ++rg)
            a[rg] = *reinterpret_cast<const bf16x8*>(
                &Xs[(16 * rg + lrow) * RS + kt * 32 + lk * 8]);
        const bool tail = (idx >= 15);
#pragma unroll
        for (int i = 0; i < 6; ++i) {
            int ct = w + 4 * i;
            if (ct < NCT) {
#pragma unroll
                for (int rg = 0; rg < 4; ++rg)
                    acc[i][rg] = __builtin_amdgcn_mfma_f32_16x16x32_bf16(a[rg], b[i], acc[i][rg], 0, 0, 0);
                if (i >= 3 && ct >= 14 && tail) {
#pragma unroll
                    for (int rg = 0; rg < 4; ++rg)
                        acch[i - 3][rg] = __builtin_amdgcn_mfma_f32_16x16x32_bf16(a[rg], b[i], acch[i - 3][rg], 0, 0, 0);
                }
            }
        }
#pragma unroll
        for (int i = 0; i < 6; ++i) b[i] = bn[i];
    }
    __syncthreads();   // Xs dead; smem becomes planes

    // epilogue in two 32-row halves: exchange via 4 f32 planes
    // plane q in {0:r-sum, 1:z-sum, 2:n-comb, 3:n-hh}; planes[(q*32+r)*PLN + col]
    for (int half = 0; half < 2; ++half) {
#pragma unroll
        for (int i = 0; i < 6; ++i) {
            int ct = w + 4 * i;
            if (ct < NCT) {
                int p = ct / 7, jm = ct - p * 7;
                int col = jm * 16 + lrow;
#pragma unroll
                for (int g = 0; g < 2; ++g) {
                    int rg = 2 * half + g;
                    int rl = g * 16 + lk * 4;
#pragma unroll
                    for (int reg = 0; reg < 4; ++reg)
                        planes[(p * 32 + rl + reg) * PLN + col] = acc[i][rg][reg];
                    if (i >= 3 && ct >= 14) {
#pragma unroll
                        for (int reg = 0; reg < 4; ++reg)
                            planes[(3 * 32 + rl + reg) * PLN + col] = acch[i - 3][rg][reg];
                    }
                }
            }
        }
        __syncthreads();
        for (int idx = tid; idx < 32 * MEMD; idx += 256) {
            int r = idx / MEMD, m = idx - r * MEMD;
            size_t node = (size_t)(nbase + half * 32 + r);
            float p0 = planes[(0 * 32 + r) * PLN + m];
            float p1 = planes[(1 * 32 + r) * PLN + m];
            float p2 = planes[(2 * 32 + r) * PLN + m];
            float p3 = planes[(3 * 32 + r) * PLN + m];
            float rgv = p0 + b_ih[m] + b_hh[m];
            float zgv = p1 + b_ih[100 + m] + b_hh[100 + m];
            float ghn = p3 + b_hh[200 + m];
            float gin = (p2 - p3) + b_ih[200 + m];
            float rr = fsigmoid(rgv);
            float zz = fsigmoid(zgv);
            float nv = ftanh(gin + rr * ghn);
            out_mem[node * MEMD + m] = (1.f - zz) * nv + zz * memory[node * MEMD + m];
        }
        __syncthreads();
    }
}

extern "C" void kernel_launch(void* const* d_in, const int* in_sizes, int n_in,
                              void* d_out, int out_size, void* d_ws, size_t ws_size,
                              hipStream_t stream) {
    const float* memory = (const float*)d_in[0];
    const float* raw_msg = (const float*)d_in[1];
    const float* time_w = (const float*)d_in[2];
    const float* time_b = (const float*)d_in[3];
    const float* w_ih = (const float*)d_in[4];
    const float* w_hh = (const float*)d_in[5];
    const float* b_ih = (const float*)d_in[6];
    const float* b_hh = (const float*)d_in[7];
    const int* last_update = (const int*)d_in[8];
    const int* src = (const int*)d_in[9];
    const int* dst = (const int*)d_in[10];
    const int* t = (const int*)d_in[11];

    char* ws = (char*)d_ws;
    unsigned long long* keys = (unsigned long long*)ws;       // 1,600,000 B
    int* other = (int*)(ws + 1600000);                        //   800,000 B
    int* ew = (int*)(ws + 2400000);                           //   800,000 B
    float* dtv = (float*)(ws + 3200000);                      //   800,000 B
    unsigned short* Wb = (unsigned short*)(ws + 4000000);     //   408,576 B

    float* out_mem = (float*)d_out;
    float* out_lu = (float*)d_out + (size_t)NN * MEMD;

    hipMemsetAsync(keys, 0, (size_t)NN * 8, stream);
    k_winner<<<(2 * EE + 255) / 256, 256, 0, stream>>>(src, dst, t, keys);
    k_nodeinfo<<<(NN + 255) / 256, 256, 0, stream>>>(keys, src, dst, last_update,
                                                     other, ew, dtv, out_lu);
    k_pack<<<(NKT * NCT * 64 + 255) / 256, 256, 0, stream>>>(w_ih, w_hh, Wb);
    k_fused<<<NN / BM, 256, 0, stream>>>(memory, raw_msg, time_w, time_b, b_ih, b_hh,
                                         other, ew, dtv, Wb, out_mem);
}

// Round 6
// 258.847 us; speedup vs baseline: 13.6656x; 1.0891x over previous
//
#include <hip/hip_runtime.h>
#include <hip/hip_bf16.h>
#include <math.h>

#define NN 200000
#define EE 100000
#define RAWD 172
#define MEMD 100
#define KTOT 608          // 480 (gi: 472 padded) + 128 (gh: 100 padded)
#define KI 480
#define NKT 19            // K steps of 32
#define NCT 21            // col tiles: 3 gates x 7 tiles (m padded 100->112)
#define RS 616            // X row stride in bf16 elems
#define BM 64             // nodes per block
#define PLN 113           // plane stride (112 + 1 pad)

typedef __attribute__((ext_vector_type(8))) short bf16x8;
typedef __attribute__((ext_vector_type(4))) float f32x4;

__device__ inline unsigned short f2bf(float v) {
    __hip_bfloat16 h = __float2bfloat16(v);
    unsigned short u; __builtin_memcpy(&u, &h, 2); return u;
}

__device__ inline ushort4 pack4(float4 v) {
    ushort4 r;
    r.x = f2bf(v.x); r.y = f2bf(v.y); r.z = f2bf(v.z); r.w = f2bf(v.w);
    return r;
}

__device__ inline float fsigmoid(float x) { return 1.f / (1.f + __expf(-x)); }
__device__ inline float ftanh(float x) { return 1.f - 2.f / (__expf(2.f * x) + 1.f); }

// Branchless cos: f64 range reduction (exact to ~5e-13 for |x|<2^22*pi/2),
// f32 sin/cos polys on [-pi/4,pi/4], quadrant select via bit tricks.
// Avoids libm's divergent Payne-Hanek path for large args.
__device__ inline float fast_cos(float x) {
    double xd = (double)x;
    double kd = rint(xd * 0.6366197723675814);      // x * 2/pi
    double r_d = fma(kd, -1.5707963267948966, xd);  // x - k*pi/2
    float r = (float)r_d;
    int ki = (int)kd;
    float s = r * r;
    // cos poly on [-pi/4,pi/4]
    float c = fmaf(s, fmaf(s, fmaf(s, fmaf(s, 2.4801587e-5f, -1.3888889e-3f),
                                   4.1666668e-2f), -0.5f), 1.0f);
    // sin poly
    float sn = r * fmaf(s, fmaf(s, fmaf(s, -1.9841270e-4f, 8.3333338e-3f),
                                -1.6666667e-1f), 1.0f);
    float base = (ki & 1) ? sn : c;
    return ((ki + 1) & 2) ? -base : base;
}

// ---- kernel 1: per-node winner via packed atomicMax key = (t<<32)|(eid+1) ----
__global__ void k_winner(const int* __restrict__ src, const int* __restrict__ dst,
                         const int* __restrict__ t, unsigned long long* __restrict__ keys) {
    int e = blockIdx.x * blockDim.x + threadIdx.x;
    if (e >= 2 * EE) return;
    int re = (e < EE) ? e : e - EE;
    int node = (e < EE) ? src[re] : dst[re];
    unsigned long long key =
        ((unsigned long long)(unsigned)t[re] << 32) | (unsigned)(e + 1);
    atomicMax(&keys[node], key);
}

// ---- kernel 2: decode winner; emit new_last_update (as f32) ----
__global__ void k_nodeinfo(const unsigned long long* __restrict__ keys,
                           const int* __restrict__ src, const int* __restrict__ dst,
                           const int* __restrict__ lu,
                           int* __restrict__ other, int* __restrict__ ew,
                           float* __restrict__ dtv, float* __restrict__ out_lu) {
    int n = blockIdx.x * blockDim.x + threadIdx.x;
    if (n >= NN) return;
    unsigned long long k = keys[n];
    if (k != 0ull) {
        int w = (int)(k & 0xffffffffull) - 1;
        int re = (w < EE) ? w : w - EE;
        other[n] = (w < EE) ? dst[re] : src[re];
        ew[n] = re;
        int tt = (int)(k >> 32);
        dtv[n] = (float)tt - (float)lu[n];
        out_lu[n] = (float)tt;
    } else {
        other[n] = 0;
        ew[n] = -1;
        dtv[n] = 0.f;
        out_lu[n] = (float)lu[n];
    }
}

// ---- kernel 3: pack W into MFMA B-fragment order, bf16 ----
__global__ void k_pack(const float* __restrict__ w_ih, const float* __restrict__ w_hh,
                       unsigned short* __restrict__ Wb) {
    int id = blockIdx.x * blockDim.x + threadIdx.x;
    if (id >= NKT * NCT * 64) return;
    int lane = id & 63;
    int ct = (id >> 6) % NCT;
    int kt = id / (64 * NCT);
    int i = lane & 15, kl = lane >> 4;
    int m = (ct % 7) * 16 + i;
    int p = ct / 7;
    unsigned short o[8];
#pragma unroll
    for (int j = 0; j < 8; ++j) {
        int k = kt * 32 + kl * 8 + j;
        float v = 0.f;
        if (m < MEMD) {
            int c = p * MEMD + m;
            if (k < 472) v = w_ih[(size_t)c * 472 + k];
            else if (k >= KI && k < KI + MEMD) v = w_hh[(size_t)c * MEMD + (k - KI)];
        }
        o[j] = f2bf(v);
    }
    uint4 v4; __builtin_memcpy(&v4, o, 16);
    *reinterpret_cast<uint4*>(Wb + (size_t)id * 8) = v4;
}

// ---- kernel 4: fused gather + bf16 MFMA dual-GEMM + GRU gates ----
// Wave w owns col-tiles ct = w, w+4, ... (6/5/5/5) for ALL 64 rows:
// each B fragment is loaded once per block (4x less L2 traffic than row-split).
__global__ __launch_bounds__(256, 2) void k_fused(
    const float* __restrict__ memory, const float* __restrict__ raw_msg,
    const float* __restrict__ time_w, const float* __restrict__ time_b,
    const float* __restrict__ b_ih, const float* __restrict__ b_hh,
    const int* __restrict__ other, const int* __restrict__ ew,
    const float* __restrict__ dtv, const unsigned short* __restrict__ Wb,
    float* __restrict__ out_mem) {
    // union: Xs (64*616*2 = 78848 B) while building/MFMA; 4 f32 planes
    // (4*32*113*4 = 57856 B) for the epilogue exchange.
    __shared__ alignas(16) char smem[BM * RS * 2];
    unsigned short* Xs = reinterpret_cast<unsigned short*>(smem);
    float* planes = reinterpret_cast<float*>(smem);
    __shared__ int s_other[BM];
    __shared__ int s_ew[BM];
    __shared__ float s_dt[BM];

    const int tid = threadIdx.x;
    const int nbase = blockIdx.x * BM;

    if (tid < BM) {
        s_other[tid] = other[nbase + tid];
        s_ew[tid] = ew[nbase + tid];
        s_dt[tid] = dtv[nbase + tid];
    }
    __syncthreads();

    const ushort4 z4 = {0, 0, 0, 0};

    // seg B: other-node memory -> k in [100,200). Random gather: issue first.
    for (int i = tid; i < BM * 25; i += 256) {
        int row = i / 25, c = i - row * 25;
        int e = s_ew[row];
        float4 v = *reinterpret_cast<const float4*>(
            memory + (size_t)s_other[row] * MEMD + 4 * c);
        ushort4 h = (e >= 0) ? pack4(v) : z4;
        *reinterpret_cast<ushort4*>(&Xs[row * RS + 100 + 4 * c]) = h;
    }
    // seg C: raw_msg -> k in [200,372). Random gather.
    for (int i = tid; i < BM * 43; i += 256) {
        int row = i / 43, c = i - row * 43;
        int e = s_ew[row];
        int eb = e < 0 ? 0 : e;
        float4 v = *reinterpret_cast<const float4*>(
            raw_msg + (size_t)eb * RAWD + 4 * c);
        ushort4 h = (e >= 0) ? pack4(v) : z4;
        *reinterpret_cast<ushort4*>(&Xs[row * RS + 200 + 4 * c]) = h;
    }
    // seg A (+E): self memory -> k in [0,100) masked, and [480,580) always.
    for (int i = tid; i < BM * 25; i += 256) {
        int row = i / 25, c = i - row * 25;
        float4 v = *reinterpret_cast<const float4*>(
            memory + (size_t)(nbase + row) * MEMD + 4 * c);
        ushort4 h = pack4(v);
        *reinterpret_cast<ushort4*>(&Xs[row * RS + KI + 4 * c]) = h;
        ushort4 hm = (s_ew[row] >= 0) ? h : z4;
        *reinterpret_cast<ushort4*>(&Xs[row * RS + 4 * c]) = hm;
    }
    // seg D: time encoding cos(dt*w+b) -> k in [372,472).
    for (int i = tid; i < BM * 25; i += 256) {
        int row = i / 25, c = i - row * 25;
        int e = s_ew[row];
        float dt = s_dt[row];
        float4 wv = *reinterpret_cast<const float4*>(time_w + 4 * c);
        float4 bv = *reinterpret_cast<const float4*>(time_b + 4 * c);
        float4 v;
        v.x = fast_cos(__fadd_rn(__fmul_rn(dt, wv.x), bv.x));
        v.y = fast_cos(__fadd_rn(__fmul_rn(dt, wv.y), bv.y));
        v.z = fast_cos(__fadd_rn(__fmul_rn(dt, wv.z), bv.z));
        v.w = fast_cos(__fadd_rn(__fmul_rn(dt, wv.w), bv.w));
        ushort4 h = (e >= 0) ? pack4(v) : z4;
        *reinterpret_cast<ushort4*>(&Xs[row * RS + 372 + 4 * c]) = h;
    }
    // zero pads: k in [472,480) and [580,608)
    for (int i = tid; i < BM * 9; i += 256) {
        int row = i / 9, c = i - row * 9;
        int k = (c < 2) ? (472 + 4 * c) : (580 + 4 * (c - 2));
        *reinterpret_cast<ushort4*>(&Xs[row * RS + k]) = z4;
    }
    __syncthreads();

    const int w = tid >> 6;
    const int l = tid & 63;
    const int lrow = l & 15, lk = l >> 4;

    f32x4 acc[6][4];           // [owned ct][rowgroup]
    f32x4 acch[3][4];          // gh-only accumulators for owned ct>=14 (i-3)
#pragma unroll
    for (int i = 0; i < 6; ++i)
#pragma unroll
        for (int rg = 0; rg < 4; ++rg) acc[i][rg] = (f32x4){0.f, 0.f, 0.f, 0.f};
#pragma unroll
    for (int i = 0; i < 3; ++i)
#pragma unroll
        for (int rg = 0; rg < 4; ++rg) acch[i][rg] = (f32x4){0.f, 0.f, 0.f, 0.f};

    const bf16x8* Wbv = reinterpret_cast<const bf16x8*>(Wb);
    const int r15 = blockIdx.x % 15;
    const int r4 = blockIdx.x & 3;

    // schedule: idx 0..14 -> rotated main k-tiles; 15..18 -> rotated tail
    auto ktof = [&](int idx) {
        if (idx < 15) { int k = r15 + idx; return k >= 15 ? k - 15 : k; }
        int k = r4 + (idx - 15); return 15 + (k >= 4 ? k - 4 : k);
    };

    bf16x8 b[6];
    {
        int kt0 = ktof(0);
#pragma unroll
        for (int i = 0; i < 6; ++i) {
            int ct = w + 4 * i;
            if (ct < NCT) b[i] = Wbv[(kt0 * NCT + ct) * 64 + l];
        }
    }

    for (int idx = 0; idx < NKT; ++idx) {
        int kt = ktof(idx);
        // 1-deep B prefetch for next k-tile
        bf16x8 bn[6];
#pragma unroll
        for (int i = 0; i < 6; ++i) bn[i] = b[i];
        if (idx + 1 < NKT) {
            int ktn = ktof(idx + 1);
#pragma unroll
            for (int i = 0; i < 6; ++i) {
                int ct = w + 4 * i;
                if (ct < NCT) bn[i] = Wbv[(ktn * NCT + ct) * 64 + l];
            }
        }
        // A fragments: all 4 rowgroups for this k-tile
        bf16x8 a[4];
#pragma unroll
        for (int rg = 0; rg < 4; ++rg)
            a[rg] = *reinterpret_cast<const bf16x8*>(
                &Xs[(16 * rg + lrow) * RS + kt * 32 + lk * 8]);
        const bool tail = (idx >= 15);
#pragma unroll
        for (int i = 0; i < 6; ++i) {
            int ct = w + 4 * i;
            if (ct < NCT) {
#pragma unroll
                for (int rg = 0; rg < 4; ++rg)
                    acc[i][rg] = __builtin_amdgcn_mfma_f32_16x16x32_bf16(a[rg], b[i], acc[i][rg], 0, 0, 0);
                if (i >= 3 && ct >= 14 && tail) {
#pragma unroll
                    for (int rg = 0; rg < 4; ++rg)
                        acch[i - 3][rg] = __builtin_amdgcn_mfma_f32_16x16x32_bf16(a[rg], b[i], acch[i - 3][rg], 0, 0, 0);
                }
            }
        }
#pragma unroll
        for (int i = 0; i < 6; ++i) b[i] = bn[i];
    }
    __syncthreads();   // Xs dead; smem becomes planes

    // epilogue in two 32-row halves: exchange via 4 f32 planes
    // plane q in {0:r-sum, 1:z-sum, 2:n-comb, 3:n-hh}; planes[(q*32+r)*PLN + col]
    for (int half = 0; half < 2; ++half) {
#pragma unroll
        for (int i = 0; i < 6; ++i) {
            int ct = w + 4 * i;
            if (ct < NCT) {
                int p = ct / 7, jm = ct - p * 7;
                int col = jm * 16 + lrow;
#pragma unroll
                for (int g = 0; g < 2; ++g) {
                    int rg = 2 * half + g;
                    int rl = g * 16 + lk * 4;
#pragma unroll
                    for (int reg = 0; reg < 4; ++reg)
                        planes[(p * 32 + rl + reg) * PLN + col] = acc[i][rg][reg];
                    if (i >= 3 && ct >= 14) {
#pragma unroll
                        for (int reg = 0; reg < 4; ++reg)
                            planes[(3 * 32 + rl + reg) * PLN + col] = acch[i - 3][rg][reg];
                    }
                }
            }
        }
        __syncthreads();
        for (int idx = tid; idx < 32 * MEMD; idx += 256) {
            int r = idx / MEMD, m = idx - r * MEMD;
            size_t node = (size_t)(nbase + half * 32 + r);
            float p0 = planes[(0 * 32 + r) * PLN + m];
            float p1 = planes[(1 * 32 + r) * PLN + m];
            float p2 = planes[(2 * 32 + r) * PLN + m];
            float p3 = planes[(3 * 32 + r) * PLN + m];
            float rgv = p0 + b_ih[m] + b_hh[m];
            float zgv = p1 + b_ih[100 + m] + b_hh[100 + m];
            float ghn = p3 + b_hh[200 + m];
            float gin = (p2 - p3) + b_ih[200 + m];
            float rr = fsigmoid(rgv);
            float zz = fsigmoid(zgv);
            float nv = ftanh(gin + rr * ghn);
            out_mem[node * MEMD + m] = (1.f - zz) * nv + zz * memory[node * MEMD + m];
        }
        __syncthreads();
    }
}

extern "C" void kernel_launch(void* const* d_in, const int* in_sizes, int n_in,
                              void* d_out, int out_size, void* d_ws, size_t ws_size,
                              hipStream_t stream) {
    const float* memory = (const float*)d_in[0];
    const float* raw_msg = (const float*)d_in[1];
    const float* time_w = (const float*)d_in[2];
    const float* time_b = (const float*)d_in[3];
    const float* w_ih = (const float*)d_in[4];
    const float* w_hh = (const float*)d_in[5];
    const float* b_ih = (const float*)d_in[6];
    const float* b_hh = (const float*)d_in[7];
    const int* last_update = (const int*)d_in[8];
    const int* src = (const int*)d_in[9];
    const int* dst = (const int*)d_in[10];
    const int* t = (const int*)d_in[11];

    char* ws = (char*)d_ws;
    unsigned long long* keys = (unsigned long long*)ws;       // 1,600,000 B
    int* other = (int*)(ws + 1600000);                        //   800,000 B
    int* ew = (int*)(ws + 2400000);                           //   800,000 B
    float* dtv = (float*)(ws + 3200000);                      //   800,000 B
    unsigned short* Wb = (unsigned short*)(ws + 4000000);     //   408,576 B

    float* out_mem = (float*)d_out;
    float* out_lu = (float*)d_out + (size_t)NN * MEMD;

    hipMemsetAsync(keys, 0, (size_t)NN * 8, stream);
    k_winner<<<(2 * EE + 255) / 256, 256, 0, stream>>>(src, dst, t, keys);
    k_nodeinfo<<<(NN + 255) / 256, 256, 0, stream>>>(keys, src, dst, last_update,
                                                     other, ew, dtv, out_lu);
    k_pack<<<(NKT * NCT * 64 + 255) / 256, 256, 0, stream>>>(w_ih, w_hh, Wb);
    k_fused<<<NN / BM, 256, 0, stream>>>(memory, raw_msg, time_w, time_b, b_ih, b_hh,
                                         other, ew, dtv, Wb, out_mem);
}

// Round 7
// 186.588 us; speedup vs baseline: 18.9578x; 1.3873x over previous
//
#include <hip/hip_runtime.h>
#include <hip/hip_bf16.h>
#include <math.h>

#define NN 200000
#define EE 100000
#define RAWD 172
#define MEMD 100
#define KTOT 608          // 480 (gi: 472 padded) + 128 (gh: 100 padded)
#define KI 480
#define NKT 19            // K steps of 32
#define NCT 21            // col tiles: 3 gates x 7 tiles (m padded 100->112)
#define RS 616            // X row stride in bf16 elems
#define BM 64             // nodes per block
#define PLN 113           // plane stride (112 + 1 pad)
#define NTHR 512          // 8 waves

typedef __attribute__((ext_vector_type(8))) short bf16x8;
typedef __attribute__((ext_vector_type(4))) float f32x4;

__device__ inline unsigned short f2bf(float v) {
    __hip_bfloat16 h = __float2bfloat16(v);
    unsigned short u; __builtin_memcpy(&u, &h, 2); return u;
}

__device__ inline ushort4 pack4(float4 v) {
    ushort4 r;
    r.x = f2bf(v.x); r.y = f2bf(v.y); r.z = f2bf(v.z); r.w = f2bf(v.w);
    return r;
}

__device__ inline float fsigmoid(float x) { return 1.f / (1.f + __expf(-x)); }
__device__ inline float ftanh(float x) { return 1.f - 2.f / (__expf(2.f * x) + 1.f); }

// Branchless cos: f64 range reduction, f32 polys, quadrant select via bit tricks.
__device__ inline float fast_cos(float x) {
    double xd = (double)x;
    double kd = rint(xd * 0.6366197723675814);      // x * 2/pi
    double r_d = fma(kd, -1.5707963267948966, xd);  // x - k*pi/2
    float r = (float)r_d;
    int ki = (int)kd;
    float s = r * r;
    float c = fmaf(s, fmaf(s, fmaf(s, fmaf(s, 2.4801587e-5f, -1.3888889e-3f),
                                   4.1666668e-2f), -0.5f), 1.0f);
    float sn = r * fmaf(s, fmaf(s, fmaf(s, -1.9841270e-4f, 8.3333338e-3f),
                                -1.6666667e-1f), 1.0f);
    float base = (ki & 1) ? sn : c;
    return ((ki + 1) & 2) ? -base : base;
}

// ---- kernel 1: per-node winner via packed atomicMax key = (t<<32)|(eid+1) ----
__global__ void k_winner(const int* __restrict__ src, const int* __restrict__ dst,
                         const int* __restrict__ t, unsigned long long* __restrict__ keys) {
    int e = blockIdx.x * blockDim.x + threadIdx.x;
    if (e >= 2 * EE) return;
    int re = (e < EE) ? e : e - EE;
    int node = (e < EE) ? src[re] : dst[re];
    unsigned long long key =
        ((unsigned long long)(unsigned)t[re] << 32) | (unsigned)(e + 1);
    atomicMax(&keys[node], key);
}

// ---- kernel 2: decode winner; emit new_last_update (as f32) ----
__global__ void k_nodeinfo(const unsigned long long* __restrict__ keys,
                           const int* __restrict__ src, const int* __restrict__ dst,
                           const int* __restrict__ lu,
                           int* __restrict__ other, int* __restrict__ ew,
                           float* __restrict__ dtv, float* __restrict__ out_lu) {
    int n = blockIdx.x * blockDim.x + threadIdx.x;
    if (n >= NN) return;
    unsigned long long k = keys[n];
    if (k != 0ull) {
        int w = (int)(k & 0xffffffffull) - 1;
        int re = (w < EE) ? w : w - EE;
        other[n] = (w < EE) ? dst[re] : src[re];
        ew[n] = re;
        int tt = (int)(k >> 32);
        dtv[n] = (float)tt - (float)lu[n];
        out_lu[n] = (float)tt;
    } else {
        other[n] = 0;
        ew[n] = -1;
        dtv[n] = 0.f;
        out_lu[n] = (float)lu[n];
    }
}

// ---- kernel 3: pack W into MFMA B-fragment order, bf16 ----
__global__ void k_pack(const float* __restrict__ w_ih, const float* __restrict__ w_hh,
                       unsigned short* __restrict__ Wb) {
    int id = blockIdx.x * blockDim.x + threadIdx.x;
    if (id >= NKT * NCT * 64) return;
    int lane = id & 63;
    int ct = (id >> 6) % NCT;
    int kt = id / (64 * NCT);
    int i = lane & 15, kl = lane >> 4;
    int m = (ct % 7) * 16 + i;
    int p = ct / 7;
    unsigned short o[8];
#pragma unroll
    for (int j = 0; j < 8; ++j) {
        int k = kt * 32 + kl * 8 + j;
        float v = 0.f;
        if (m < MEMD) {
            int c = p * MEMD + m;
            if (k < 472) v = w_ih[(size_t)c * 472 + k];
            else if (k >= KI && k < KI + MEMD) v = w_hh[(size_t)c * MEMD + (k - KI)];
        }
        o[j] = f2bf(v);
    }
    uint4 v4; __builtin_memcpy(&v4, o, 16);
    *reinterpret_cast<uint4*>(Wb + (size_t)id * 8) = v4;
}

// ---- kernel 4: fused gather + bf16 MFMA dual-GEMM + GRU gates ----
// 8 waves; wave w owns col-tiles ct = w, w+8, w+16 (<21) for ALL 64 rows.
// B fragments still loaded exactly once per block; 4 waves/SIMD for latency hiding.
__global__ __launch_bounds__(NTHR, 4) void k_fused(
    const float* __restrict__ memory, const float* __restrict__ raw_msg,
    const float* __restrict__ time_w, const float* __restrict__ time_b,
    const float* __restrict__ b_ih, const float* __restrict__ b_hh,
    const int* __restrict__ other, const int* __restrict__ ew,
    const float* __restrict__ dtv, const unsigned short* __restrict__ Wb,
    float* __restrict__ out_mem) {
    __shared__ alignas(16) char smem[BM * RS * 2];
    unsigned short* Xs = reinterpret_cast<unsigned short*>(smem);
    float* planes = reinterpret_cast<float*>(smem);
    __shared__ int s_other[BM];
    __shared__ int s_ew[BM];
    __shared__ float s_dt[BM];

    const int tid = threadIdx.x;
    const int nbase = blockIdx.x * BM;

    if (tid < BM) {
        s_other[tid] = other[nbase + tid];
        s_ew[tid] = ew[nbase + tid];
        s_dt[tid] = dtv[nbase + tid];
    }
    __syncthreads();

    const ushort4 z4 = {0, 0, 0, 0};

    // seg B: other-node memory -> k in [100,200). Random gather: issue first.
    for (int i = tid; i < BM * 25; i += NTHR) {
        int row = i / 25, c = i - row * 25;
        int e = s_ew[row];
        float4 v = *reinterpret_cast<const float4*>(
            memory + (size_t)s_other[row] * MEMD + 4 * c);
        ushort4 h = (e >= 0) ? pack4(v) : z4;
        *reinterpret_cast<ushort4*>(&Xs[row * RS + 100 + 4 * c]) = h;
    }
    // seg C: raw_msg -> k in [200,372). Random gather.
    for (int i = tid; i < BM * 43; i += NTHR) {
        int row = i / 43, c = i - row * 43;
        int e = s_ew[row];
        int eb = e < 0 ? 0 : e;
        float4 v = *reinterpret_cast<const float4*>(
            raw_msg + (size_t)eb * RAWD + 4 * c);
        ushort4 h = (e >= 0) ? pack4(v) : z4;
        *reinterpret_cast<ushort4*>(&Xs[row * RS + 200 + 4 * c]) = h;
    }
    // seg A (+E): self memory -> k in [0,100) masked, and [480,580) always.
    for (int i = tid; i < BM * 25; i += NTHR) {
        int row = i / 25, c = i - row * 25;
        float4 v = *reinterpret_cast<const float4*>(
            memory + (size_t)(nbase + row) * MEMD + 4 * c);
        ushort4 h = pack4(v);
        *reinterpret_cast<ushort4*>(&Xs[row * RS + KI + 4 * c]) = h;
        ushort4 hm = (s_ew[row] >= 0) ? h : z4;
        *reinterpret_cast<ushort4*>(&Xs[row * RS + 4 * c]) = hm;
    }
    // seg D: time encoding cos(dt*w+b) -> k in [372,472).
    for (int i = tid; i < BM * 25; i += NTHR) {
        int row = i / 25, c = i - row * 25;
        int e = s_ew[row];
        float dt = s_dt[row];
        float4 wv = *reinterpret_cast<const float4*>(time_w + 4 * c);
        float4 bv = *reinterpret_cast<const float4*>(time_b + 4 * c);
        float4 v;
        v.x = fast_cos(__fadd_rn(__fmul_rn(dt, wv.x), bv.x));
        v.y = fast_cos(__fadd_rn(__fmul_rn(dt, wv.y), bv.y));
        v.z = fast_cos(__fadd_rn(__fmul_rn(dt, wv.z), bv.z));
        v.w = fast_cos(__fadd_rn(__fmul_rn(dt, wv.w), bv.w));
        ushort4 h = (e >= 0) ? pack4(v) : z4;
        *reinterpret_cast<ushort4*>(&Xs[row * RS + 372 + 4 * c]) = h;
    }
    // zero pads: k in [472,480) and [580,608)
    for (int i = tid; i < BM * 9; i += NTHR) {
        int row = i / 9, c = i - row * 9;
        int k = (c < 2) ? (472 + 4 * c) : (580 + 4 * (c - 2));
        *reinterpret_cast<ushort4*>(&Xs[row * RS + k]) = z4;
    }
    __syncthreads();

    const int w = tid >> 6;
    const int l = tid & 63;
    const int lrow = l & 15, lk = l >> 4;

    f32x4 acc[3][4];           // [owned ct][rowgroup]
    f32x4 acch[4];             // gh-only accumulator (each wave owns <=1 ct>=14)
#pragma unroll
    for (int i = 0; i < 3; ++i)
#pragma unroll
        for (int rg = 0; rg < 4; ++rg) acc[i][rg] = (f32x4){0.f, 0.f, 0.f, 0.f};
#pragma unroll
    for (int rg = 0; rg < 4; ++rg) acch[rg] = (f32x4){0.f, 0.f, 0.f, 0.f};

    const bf16x8* Wbv = reinterpret_cast<const bf16x8*>(Wb);
    const int r15 = blockIdx.x % 15;
    const int r4 = blockIdx.x & 3;

    auto ktof = [&](int idx) {
        if (idx < 15) { int k = r15 + idx; return k >= 15 ? k - 15 : k; }
        int k = r4 + (idx - 15); return 15 + (k >= 4 ? k - 4 : k);
    };

    bf16x8 b[3];
    {
        int kt0 = ktof(0);
#pragma unroll
        for (int i = 0; i < 3; ++i) {
            int ct = w + 8 * i;
            if (ct < NCT) b[i] = Wbv[(kt0 * NCT + ct) * 64 + l];
        }
    }

    for (int idx = 0; idx < NKT; ++idx) {
        int kt = ktof(idx);
        // 1-deep B prefetch for next k-tile
        bf16x8 bn[3];
#pragma unroll
        for (int i = 0; i < 3; ++i) bn[i] = b[i];
        if (idx + 1 < NKT) {
            int ktn = ktof(idx + 1);
#pragma unroll
            for (int i = 0; i < 3; ++i) {
                int ct = w + 8 * i;
                if (ct < NCT) bn[i] = Wbv[(ktn * NCT + ct) * 64 + l];
            }
        }
        // A fragments: all 4 rowgroups for this k-tile
        bf16x8 a[4];
#pragma unroll
        for (int rg = 0; rg < 4; ++rg)
            a[rg] = *reinterpret_cast<const bf16x8*>(
                &Xs[(16 * rg + lrow) * RS + kt * 32 + lk * 8]);
        const bool tail = (idx >= 15);
#pragma unroll
        for (int i = 0; i < 3; ++i) {
            int ct = w + 8 * i;
            if (ct < NCT) {
#pragma unroll
                for (int rg = 0; rg < 4; ++rg)
                    acc[i][rg] = __builtin_amdgcn_mfma_f32_16x16x32_bf16(a[rg], b[i], acc[i][rg], 0, 0, 0);
                if (ct >= 14 && tail) {
#pragma unroll
                    for (int rg = 0; rg < 4; ++rg)
                        acch[rg] = __builtin_amdgcn_mfma_f32_16x16x32_bf16(a[rg], b[i], acch[rg], 0, 0, 0);
                }
            }
        }
#pragma unroll
        for (int i = 0; i < 3; ++i) b[i] = bn[i];
    }
    __syncthreads();   // Xs dead; smem becomes planes

    // epilogue in two 32-row halves: exchange via 4 f32 planes
    // plane q in {0:r, 1:z, 2:n-comb, 3:n-hh}; planes[(q*32+r)*PLN + col]
    for (int half = 0; half < 2; ++half) {
#pragma unroll
        for (int i = 0; i < 3; ++i) {
            int ct = w + 8 * i;
            if (ct < NCT) {
                int p = ct / 7, jm = ct - p * 7;
                int col = jm * 16 + lrow;
#pragma unroll
                for (int g = 0; g < 2; ++g) {
                    int rg = 2 * half + g;
                    int rl = g * 16 + lk * 4;
#pragma unroll
                    for (int reg = 0; reg < 4; ++reg)
                        planes[(p * 32 + rl + reg) * PLN + col] = acc[i][rg][reg];
                    if (ct >= 14) {
#pragma unroll
                        for (int reg = 0; reg < 4; ++reg)
                            planes[(3 * 32 + rl + reg) * PLN + col] = acch[rg][reg];
                    }
                }
            }
        }
        __syncthreads();
        for (int idx = tid; idx < 32 * MEMD; idx += NTHR) {
            int r = idx / MEMD, m = idx - r * MEMD;
            size_t node = (size_t)(nbase + half * 32 + r);
            float p0 = planes[(0 * 32 + r) * PLN + m];
            float p1 = planes[(1 * 32 + r) * PLN + m];
            float p2 = planes[(2 * 32 + r) * PLN + m];
            float p3 = planes[(3 * 32 + r) * PLN + m];
            float rgv = p0 + b_ih[m] + b_hh[m];
            float zgv = p1 + b_ih[100 + m] + b_hh[100 + m];
            float ghn = p3 + b_hh[200 + m];
            float gin = (p2 - p3) + b_ih[200 + m];
            float rr = fsigmoid(rgv);
            float zz = fsigmoid(zgv);
            float nv = ftanh(gin + rr * ghn);
            out_mem[node * MEMD + m] = (1.f - zz) * nv + zz * memory[node * MEMD + m];
        }
        __syncthreads();
    }
}

extern "C" void kernel_launch(void* const* d_in, const int* in_sizes, int n_in,
                              void* d_out, int out_size, void* d_ws, size_t ws_size,
                              hipStream_t stream) {
    const float* memory = (const float*)d_in[0];
    const float* raw_msg = (const float*)d_in[1];
    const float* time_w = (const float*)d_in[2];
    const float* time_b = (const float*)d_in[3];
    const float* w_ih = (const float*)d_in[4];
    const float* w_hh = (const float*)d_in[5];
    const float* b_ih = (const float*)d_in[6];
    const float* b_hh = (const float*)d_in[7];
    const int* last_update = (const int*)d_in[8];
    const int* src = (const int*)d_in[9];
    const int* dst = (const int*)d_in[10];
    const int* t = (const int*)d_in[11];

    char* ws = (char*)d_ws;
    unsigned long long* keys = (unsigned long long*)ws;       // 1,600,000 B
    int* other = (int*)(ws + 1600000);                        //   800,000 B
    int* ew = (int*)(ws + 2400000);                           //   800,000 B
    float* dtv = (float*)(ws + 3200000);                      //   800,000 B
    unsigned short* Wb = (unsigned short*)(ws + 4000000);     //   408,576 B

    float* out_mem = (float*)d_out;
    float* out_lu = (float*)d_out + (size_t)NN * MEMD;

    hipMemsetAsync(keys, 0, (size_t)NN * 8, stream);
    k_winner<<<(2 * EE + 255) / 256, 256, 0, stream>>>(src, dst, t, keys);
    k_nodeinfo<<<(NN + 255) / 256, 256, 0, stream>>>(keys, src, dst, last_update,
                                                     other, ew, dtv, out_lu);
    k_pack<<<(NKT * NCT * 64 + 255) / 256, 256, 0, stream>>>(w_ih, w_hh, Wb);
    k_fused<<<NN / BM, NTHR, 0, stream>>>(memory, raw_msg, time_w, time_b, b_ih, b_hh,
                                          other, ew, dtv, Wb, out_mem);
}